// Round 13
// baseline (84.619 us; speedup 1.0000x reference)
//
#include <hip/hip_runtime.h>
#include <hip/hip_bf16.h>

#define N_B   4
#define C_IN  128
#define HWSZ  4096
#define C_M   256

typedef __attribute__((ext_vector_type(8))) short          s16x8;   // bf16x8 frag (4 VGPR)
typedef __attribute__((ext_vector_type(8))) unsigned short u16x8;
typedef __attribute__((ext_vector_type(4))) unsigned short u16x4;
typedef __attribute__((ext_vector_type(4))) float          f32x4;

__device__ __forceinline__ unsigned short f2bf(float f) {
    union { float f; unsigned u; } v; v.f = f;
    unsigned r = v.u + 0x7fffu + ((v.u >> 16) & 1u);   // RNE
    return (unsigned short)(r >> 16);
}
__device__ __forceinline__ float bf2f(unsigned short u) {
    union { unsigned u; float f; } v; v.u = ((unsigned)u) << 16; return v.f;
}

// ---------------------------------------------------------------------------
// K1: fused prep. Blocks 0..255: img transpose (n,ci,h,w)->bf16 (n,h,w,ci).
// Blocks 256..2815: fragment-ordered weights.
//  w1f[z2][cc4][tap9][g9][lane64][j8]; row=g*16+(lane&15), ci=cc*32+(lane>>4)*8+j
//  w2f HALF-TILE layout [uvt8 32][t5][ks8][lane64][j8]:
//    A-tile t rows = (k = 2t + (ln>>3), uv = uvt8*8 + (ln&7)); k=9 rows = 0 (pad).
//    value = 0.25 * mk_w2[(k*256+uv)*256 + ks*32 + (lane>>4)*8 + j]
// ---------------------------------------------------------------------------
__global__ void __launch_bounds__(256)
prep_all(const float* __restrict__ img,
         const float* __restrict__ mk_w1, const float* __restrict__ fh_w1,
         const float* __restrict__ mk_w2,
         unsigned short* __restrict__ imgT,
         unsigned short* __restrict__ w1f, unsigned short* __restrict__ w2f)
{
    __shared__ float s[128][65];
    const int b = blockIdx.x;
    if (b < 256) {
        const int n = b >> 6, h = b & 63;
        const float* src = img + (size_t)n * C_IN * HWSZ + h * 64;
        for (int i = threadIdx.x; i < 128 * 64; i += 256) {
            int ci = i >> 6, w = i & 63;
            s[ci][w] = src[(size_t)ci * HWSZ + w];
        }
        __syncthreads();
        unsigned short* dst = imgT + ((size_t)(n * 64 + h) * 64) * 128;
        for (int i = threadIdx.x; i < 64 * 128; i += 256) {
            int w = i >> 7, ci = i & 127;
            dst[(size_t)w * 128 + ci] = f2bf(s[ci][w]);
        }
        return;
    }
    int i = (b - 256) * 256 + threadIdx.x;
    if (i < 32 * 20480) {
        int uvt8 = i / 20480;
        int r    = i - uvt8 * 20480;
        int t    = r / 4096;
        int r2   = r - t * 4096;
        int ks   = r2 >> 9;
        int lane = (r2 >> 3) & 63;
        int j    = r2 & 7;
        int lg = lane >> 4, ln = lane & 15;
        int k  = 2 * t + (ln >> 3);
        int uv = uvt8 * 8 + (ln & 7);
        int ci = ks * 32 + lg * 8 + j;
        w2f[i] = (k < 9) ? f2bf(0.25f * mk_w2[(size_t)(k * 256 + uv) * 256 + ci])
                         : (unsigned short)0;
    }
    if (i < 2 * 4 * 9 * 9 * 512) {
        int z   = i / 165888;
        int r   = i - z * 165888;
        int cc  = r / 41472;
        int r2  = r - cc * 41472;
        int tap = r2 / 4608;
        int r3  = r2 - tap * 4608;
        int g   = r3 / 512;
        int r4  = r3 - g * 512;
        int lane = r4 >> 3, j = r4 & 7;
        int lg = lane >> 4, ln = lane & 15;
        int row = g * 16 + ln;
        int ci  = cc * 32 + lg * 8 + j;
        float w = 0.f;
        if (z == 0) {
            if (row < 128)      w = mk_w1[((size_t)row * C_IN + ci) * 9 + tap];
            else if (row < 130) w = fh_w1[((size_t)(row - 128) * C_IN + ci) * 9 + tap];
        } else {
            if (row < 128)      w = mk_w1[((size_t)(128 + row) * C_IN + ci) * 9 + tap];
        }
        w1f[i] = f2bf(w);
    }
}

// ---------------------------------------------------------------------------
// K2: conv1 implicit-GEMM 3x3 (unchanged, known-good).
// ---------------------------------------------------------------------------
__global__ void __launch_bounds__(512, 4)
conv1_mfma(const unsigned short* __restrict__ imgT,
           const unsigned short* __restrict__ w1f,
           const float* __restrict__ mk_b1, const float* __restrict__ fh_b1,
           unsigned short* __restrict__ m_frag, float* __restrict__ h_pre,
           float* __restrict__ ps_s, float* __restrict__ ps_s2)
{
    __shared__ unsigned short s_img[3][66][40];   // 15,840 B
    __shared__ float s_bias[144];
    __shared__ float s_ps[2][144], s_ps2[2][144];

    const int hw = blockIdx.x;
    const int xcd = hw & 7, slot = hw >> 3;
    const int lid = xcd * 64 + slot;
    const int n = lid >> 7, h = (lid >> 1) & 63, z = lid & 1;
    const int hn = n * 64 + h;

    const int tid = threadIdx.x;
    const int wv = tid >> 6, lane = tid & 63;
    const int lg = lane >> 4, ln = lane & 15;
    const int gq = wv >> 1, half = wv & 1;
    const int g0 = z ? (gq * 2) : ((int[4]){0, 3, 5, 7})[gq];
    const int gn = z ? 2 : ((int[4]){3, 2, 2, 2})[gq];

    if (tid < 144) {
        float b = 0.f;
        if (z == 0) {
            if (tid < 128)      b = mk_b1[tid];
            else if (tid < 130) b = fh_b1[tid - 128];
        } else if (tid < 128)   b = mk_b1[128 + tid];
        s_bias[tid] = b;
    }

    f32x4 acc[3][2];
#pragma unroll
    for (int g = 0; g < 3; ++g)
#pragma unroll
        for (int q = 0; q < 2; ++q) acc[g][q] = (f32x4){0.f, 0.f, 0.f, 0.f};

    for (int cc = 0; cc < 4; ++cc) {
        __syncthreads();
        for (int i = tid; i < 3 * 66 * 4; i += 512) {
            int r = i / 264;
            int rem = i - r * 264;
            int c = rem >> 2, un = rem & 3;
            int gy = h - 1 + r, gx = c - 1;
            u16x8 v = {0, 0, 0, 0, 0, 0, 0, 0};
            if ((unsigned)gy < 64u && (unsigned)gx < 64u)
                v = *(const u16x8*)&imgT[((size_t)((n * 64 + gy) * 64 + gx)) * 128 + cc * 32 + un * 8];
            *(u16x8*)&s_img[r][c][un * 8] = v;
        }
        __syncthreads();

        const unsigned short* wfp = w1f + (size_t)(z * 4 + cc) * 81 * 512 + lane * 8;
#pragma unroll
        for (int tap = 0; tap < 9; ++tap) {
            const int dy = tap / 3, dx = tap % 3;
            s16x8 bf[2];
#pragma unroll
            for (int q = 0; q < 2; ++q)
                bf[q] = *(const s16x8*)&s_img[dy][half * 32 + q * 16 + ln + dx][lg * 8];
#pragma unroll
            for (int gi = 0; gi < 3; ++gi) {
                if (gi < gn) {
                    s16x8 af = *(const s16x8*)&wfp[(size_t)(tap * 9 + g0 + gi) * 512];
#pragma unroll
                    for (int q = 0; q < 2; ++q)
                        acc[gi][q] = __builtin_amdgcn_mfma_f32_16x16x32_bf16(af, bf[q], acc[gi][q], 0, 0, 0);
                }
            }
        }
    }

    // epilogue: stores + per-channel partial stats
#pragma unroll
    for (int gi = 0; gi < 3; ++gi) {
        if (gi >= gn) continue;
        const int g = g0 + gi;
        float v[2][4];
#pragma unroll
        for (int q = 0; q < 2; ++q)
#pragma unroll
            for (int r = 0; r < 4; ++r)
                v[q][r] = acc[gi][q][r] + s_bias[g * 16 + lg * 4 + r];
        // stores
#pragma unroll
        for (int q = 0; q < 2; ++q) {
            const int px  = half * 32 + q * 16 + ln;
            const int pxg = h * 4 + half * 2 + q;
            if (z == 0 && g == 8) {
                if (lg == 0) {
#pragma unroll
                    for (int r = 0; r < 2; ++r)
                        h_pre[((size_t)(n * 2 + r)) * HWSZ + h * 64 + px] = v[q][r];
                }
            } else {
                u16x4 vv;
#pragma unroll
                for (int r = 0; r < 4; ++r) vv[r] = f2bf(v[q][r]);
                int ks  = z * 4 + (g >> 1);
                int lgp = ((g & 1) * 2 + (lg >> 1)) & 3;
                size_t off = ((((size_t)(n * 256 + pxg) * 8 + ks) * 4 + lgp) * 128) + ln * 8 + (lg & 1) * 4;
                *(u16x4*)&m_frag[off] = vv;
            }
        }
        // partial stats
#pragma unroll
        for (int r = 0; r < 4; ++r) {
            float s  = v[0][r] + v[1][r];
            float s2 = v[0][r] * v[0][r] + v[1][r] * v[1][r];
#pragma unroll
            for (int off = 1; off < 16; off <<= 1) {
                s  += __shfl_xor(s,  off, 64);
                s2 += __shfl_xor(s2, off, 64);
            }
            if (ln == 0) {
                s_ps[half][g * 16 + lg * 4 + r]  = s;
                s_ps2[half][g * 16 + lg * 4 + r] = s2;
            }
        }
    }
    __syncthreads();
    const int nch = z ? 128 : 130;
    if (tid < nch) {
        const int idx = z * 146 + tid;
        ps_s[(size_t)idx * 256 + hn]  = s_ps[0][tid] + s_ps[1][tid];
        ps_s2[(size_t)idx * 256 + hn] = s_ps2[0][tid] + s_ps2[1][tid];
    }
}

// ---------------------------------------------------------------------------
// K3: final BN stat reduction, one block per channel (258), 64 thr.
// ---------------------------------------------------------------------------
__global__ void __launch_bounds__(64)
bn_final2(const float* __restrict__ ps_s, const float* __restrict__ ps_s2,
          const float* __restrict__ mk_g, const float* __restrict__ mk_be,
          const float* __restrict__ fh_g, const float* __restrict__ fh_be,
          float* __restrict__ ab_m, float* __restrict__ ab_h)
{
    const int b = blockIdx.x;
    const int idx = (b < 256) ? ((b >> 7) * 146 + (b & 127)) : (128 + (b - 256));
    const int t = threadIdx.x;
    float S = 0.f, S2 = 0.f;
    const float* p1 = ps_s  + (size_t)idx * 256;
    const float* p2 = ps_s2 + (size_t)idx * 256;
    for (int i = t; i < 256; i += 64) { S += p1[i]; S2 += p2[i]; }
#pragma unroll
    for (int off = 32; off > 0; off >>= 1) {
        S += __shfl_down(S, off, 64); S2 += __shfl_down(S2, off, 64);
    }
    if (t == 0) {
        const float inv = 1.0f / (float)(N_B * HWSZ);
        float mu = S * inv;
        float var = S2 * inv - mu * mu;
        float r = rsqrtf(var + 1e-5f);
        if (b < 256) {
            float a = mk_g[b] * r;
            ab_m[2 * b] = a; ab_m[2 * b + 1] = mk_be[b] - mu * a;
        } else {
            int c = b - 256;
            float a = fh_g[c] * r;
            ab_h[2 * c] = a; ab_h[2 * c + 1] = fh_be[c] - mu * a;
        }
    }
}

// ---------------------------------------------------------------------------
// K4: blocks 0..2047 in-place BN+ReLU on m_frag; blocks 2048..2175 flow conv2.
// ---------------------------------------------------------------------------
__global__ void __launch_bounds__(256)
bnrelu_flow(unsigned short* __restrict__ m_frag, const float* __restrict__ ab,
            const float* __restrict__ hpre, const float* __restrict__ ab_h,
            const float* __restrict__ w2, const float* __restrict__ b2,
            float* __restrict__ flow8)
{
    __shared__ float s_ab[512];
    const int t = threadIdx.x;
    if (blockIdx.x < 2048) {
        s_ab[t] = ab[t]; s_ab[256 + t] = ab[256 + t];
        __syncthreads();
        const unsigned u = blockIdx.x * 256 + t;
        const int lg = (u >> 4) & 3, ks = (u >> 7) & 7;
        const int cb = ks * 32 + lg * 8;
        u16x8 v = *(const u16x8*)&m_frag[(size_t)u * 8];
        u16x8 o;
#pragma unroll
        for (int j = 0; j < 8; ++j) {
            float a = s_ab[2 * (cb + j)], b = s_ab[2 * (cb + j) + 1];
            o[j] = f2bf(fmaxf(a * bf2f(v[j]) + b, 0.f));
        }
        *(u16x8*)&m_frag[(size_t)u * 8] = o;
        return;
    }
    int idx = (blockIdx.x - 2048) * 256 + t;
    int w = idx & 63, h = (idx >> 6) & 63, co = (idx >> 12) & 1, n = idx >> 13;
    float acc = b2[co];
#pragma unroll
    for (int ci = 0; ci < 2; ++ci) {
        float a = ab_h[2 * ci], b = ab_h[2 * ci + 1];
        const float* p = hpre + (size_t)(n * 2 + ci) * HWSZ;
        const float* wp = &w2[(co * 2 + ci) * 9];
#pragma unroll
        for (int dy = 0; dy < 3; ++dy)
#pragma unroll
            for (int dx = 0; dx < 3; ++dx) {
                int gy = h + dy - 1, gx = w + dx - 1;
                float v = 0.f;
                if ((unsigned)gy < 64u && (unsigned)gx < 64u)
                    v = fmaxf(a * p[gy * 64 + gx] + b, 0.f);
                acc += wp[dy * 3 + dx] * v;
            }
    }
    flow8[idx] = acc * 8.0f;
}

// ---------------------------------------------------------------------------
// K5: fused 1x1-conv GEMM + bias + softmax(9) + convex upsample.
// R13: A-tiles = (k-pair x 8 uv), 5 tiles (k padded to 10; pad bias=-1e30 ->
// p=0 exactly). Wave q=2 -> acc[5][2] = 40 AGPR, ~85 regs, (512,4) NO SPILL,
// 2-3 blocks/CU. Softmax k's split even/odd across lane^32 pairs; merged via
// 4 exact in-wave __shfl_xor(.,32): max, sum, a0/a1 partials. af reuse=2
// (655 MB LDS, under the 10.4us MFMA floor).
// Block = 512 thr = (row_l 0..3, half 0..1); covers 4 rows x 64 px, 8 uv.
// Grid 2048 = 16 hb x 32 uvt8 x 4 n.
// ---------------------------------------------------------------------------
__global__ void __launch_bounds__(512, 4)
mask_combine_mfma(const unsigned short* __restrict__ m_frag,
                  const unsigned short* __restrict__ w2f,
                  const float* __restrict__ mk_b2,
                  const float* __restrict__ flow8,
                  float* __restrict__ out)
{
    __shared__ unsigned short s_w[20480];       // 40 KB: [t5][ks8][lane64][j8]
    __shared__ float s_fl[2][6][66];            // 3,168 B
    __shared__ float s_bias[10][8];             // 320 B

    const int id = blockIdx.x;
    const int hb = id & 15, uvt8 = (id >> 4) & 31, n = id >> 9;

    const int tid = threadIdx.x;
    const int wv = tid >> 6, lane = tid & 63;
    const int lg = lane >> 4, ln = lane & 15;
    const int row_l = wv >> 1, half = wv & 1;
    const int h = hb * 4 + row_l;
    const int khalf = lg >> 1;      // 0: C-rows 0-7 (even k), 1: rows 8-15 (odd k)

    // stage W half-tile (linear copy)
    {
        const u16x8* wsrc = (const u16x8*)(w2f + (size_t)uvt8 * 20480);
        u16x8* wdst = (u16x8*)s_w;
        for (int i = tid; i < 2560; i += 512) wdst[i] = wsrc[i];
    }
    // stage flow rows hb*4-1 .. hb*4+4
    for (int i = tid; i < 2 * 6 * 66; i += 512) {
        int c = i / 396, rem = i - c * 396, r = rem / 66, col = rem - r * 66;
        int gy = hb * 4 - 1 + r, gx = col - 1;
        float v = 0.f;
        if ((unsigned)gy < 64u && (unsigned)gx < 64u)
            v = flow8[((size_t)(n * 2 + c)) * HWSZ + gy * 64 + gx];
        s_fl[c][r][col] = v;
    }
    if (tid < 80) {
        int k = tid >> 3, uvl = tid & 7;
        s_bias[k][uvl] = (k < 9) ? 0.25f * mk_b2[k * 256 + uvt8 * 8 + uvl] : -1e30f;
    }
    __syncthreads();

    const unsigned short* wk0 = s_w + lg * 128 + ln * 8;
    const unsigned short* mb = m_frag + (size_t)(n * 256 + h * 4 + half * 2) * 4096 + lg * 128 + ln * 8;

    f32x4 acc[5][2];
#pragma unroll
    for (int t = 0; t < 5; ++t)
#pragma unroll
        for (int q = 0; q < 2; ++q) acc[t][q] = (f32x4){0.f, 0.f, 0.f, 0.f};

    // rolling 2-deep B prefetch (R11-proven pattern)
    s16x8 bq[2][2];
#pragma unroll
    for (int d = 0; d < 2; ++d)
#pragma unroll
        for (int q = 0; q < 2; ++q) bq[d][q] = *(const s16x8*)&mb[q * 4096 + d * 512];

#pragma unroll
    for (int ks = 0; ks < 8; ++ks) {
        const int d = ks & 1;
#pragma unroll
        for (int t = 0; t < 5; ++t) {
            s16x8 af = *(const s16x8*)&wk0[(t * 8 + ks) * 512];
#pragma unroll
            for (int q = 0; q < 2; ++q)
                acc[t][q] = __builtin_amdgcn_mfma_f32_16x16x32_bf16(af, bq[d][q], acc[t][q], 0, 0, 0);
        }
        if (ks < 6) {
#pragma unroll
            for (int q = 0; q < 2; ++q)
                bq[d][q] = *(const s16x8*)&mb[q * 4096 + (ks + 2) * 512];
        }
    }

    // epilogue: split-k softmax via lane^32 exchange (exact, in-wave)
    const int dyE[5] = {0, 0, 1, 2, 2}, dxE[5] = {0, 2, 1, 0, 2};   // k = 0,2,4,6,8
    const int dyO[5] = {0, 1, 1, 2, 2}, dxO[5] = {1, 0, 2, 1, 2};   // k = 1,3,5,7,(9->k8 clamp)

#pragma unroll
    for (int q = 0; q < 2; ++q) {
        const int wpx = half * 32 + q * 16 + ln;
        float o[4];
#pragma unroll
        for (int r = 0; r < 4; ++r) {
            const int uvl = (lg & 1) * 4 + r;
            float v5[5], mx = -1e30f;
#pragma unroll
            for (int t = 0; t < 5; ++t) {
                v5[t] = acc[t][q][r] + s_bias[2 * t + khalf][uvl];
                mx = fmaxf(mx, v5[t]);
            }
            mx = fmaxf(mx, __shfl_xor(mx, 32, 64));
            float p5[5], s5 = 0.f;
#pragma unroll
            for (int t = 0; t < 5; ++t) { p5[t] = __expf(v5[t] - mx); s5 += p5[t]; }
            float sum = s5 + __shfl_xor(s5, 32, 64);
            float a0 = 0.f, a1 = 0.f;
#pragma unroll
            for (int t = 0; t < 5; ++t) {
                const int dy = khalf ? dyO[t] : dyE[t];
                const int dx = khalf ? dxO[t] : dxE[t];
                a0 += p5[t] * s_fl[0][row_l + dy][wpx + dx];
                a1 += p5[t] * s_fl[1][row_l + dy][wpx + dx];
            }
            a0 += __shfl_xor(a0, 32, 64);
            a1 += __shfl_xor(a1, 32, 64);
            const float inv = 1.0f / sum;
            o[r] = (khalf ? a1 : a0) * inv;      // lane stores channel c = khalf
        }
        float* base = out + ((size_t)(n * 2 + khalf) * 1024 + h * 16 + (uvt8 >> 1)) * 1024
                      + wpx * 16 + (uvt8 & 1) * 8 + (lg & 1) * 4;
        *(f32x4*)base = (f32x4){o[0], o[1], o[2], o[3]};
    }
}

// ---------------------------------------------------------------------------
extern "C" void kernel_launch(void* const* d_in, const int* in_sizes, int n_in,
                              void* d_out, int out_size, void* d_ws, size_t ws_size,
                              hipStream_t stream) {
    const float* img   = (const float*)d_in[0];
    const float* fh_w1 = (const float*)d_in[1];
    const float* fh_b1 = (const float*)d_in[2];
    const float* fh_g  = (const float*)d_in[3];
    const float* fh_be = (const float*)d_in[4];
    const float* fh_w2 = (const float*)d_in[5];
    const float* fh_b2 = (const float*)d_in[6];
    const float* mk_w1 = (const float*)d_in[7];
    const float* mk_b1 = (const float*)d_in[8];
    const float* mk_g  = (const float*)d_in[9];
    const float* mk_be = (const float*)d_in[10];
    const float* mk_w2 = (const float*)d_in[11];
    const float* mk_b2 = (const float*)d_in[12];
    float* out = (float*)d_out;

    char* p = (char*)d_ws;
    unsigned short* w2f    = (unsigned short*)p;  p += (size_t)1310720;   // 32*20480*2
    unsigned short* w1f    = (unsigned short*)p;  p += (size_t)663552;
    unsigned short* imgT   = (unsigned short*)p;  p += (size_t)4194304;
    unsigned short* m_frag = (unsigned short*)p;  p += (size_t)8388608;
    float* h_pre  = (float*)p;  p += (size_t)131072;
    float* flow8  = (float*)p;  p += (size_t)131072;
    float* ps_s   = (float*)p;  p += (size_t)280576;
    float* ps_s2  = (float*)p;  p += (size_t)280576;
    float* ab_m   = (float*)p;  p += 2048;
    float* ab_h   = (float*)p;  p += 64;

    prep_all<<<2816, 256, 0, stream>>>(img, mk_w1, fh_w1, mk_w2, imgT, w1f, w2f);
    conv1_mfma<<<512, 512, 0, stream>>>(imgT, w1f, mk_b1, fh_b1, m_frag, h_pre, ps_s, ps_s2);
    bn_final2<<<258, 64, 0, stream>>>(ps_s, ps_s2, mk_g, mk_be, fh_g, fh_be, ab_m, ab_h);
    bnrelu_flow<<<2176, 256, 0, stream>>>(m_frag, ab_m, h_pre, ab_h, fh_w2, fh_b2, flow8);
    mask_combine_mfma<<<2048, 512, 0, stream>>>(m_frag, w2f, mk_b2, flow8, out);
}